// Round 1
// baseline (4798.987 us; speedup 1.0000x reference)
//
#include <hip/hip_runtime.h>
#include <math.h>

// ---------------------------------------------------------------------------
// VAE_Gumbel: B=4096, D=5000, H=512, Z=64, fp32 throughout (round 1 baseline)
// out = [mu_x (4096x5000), mu_latent (4096x64), logvar_latent (4096x64)]
// ---------------------------------------------------------------------------

#define TILE 64
#define GBK  16
#define LDP  (TILE + 4)   // pad to 68 floats: rows stay 16B-aligned, 2-way-max bank aliasing (free)

__device__ __forceinline__ float wave_max64(float v) {
#pragma unroll
    for (int off = 32; off > 0; off >>= 1) v = fmaxf(v, __shfl_xor(v, off, 64));
    return v;
}
__device__ __forceinline__ float wave_sum64(float v) {
#pragma unroll
    for (int off = 32; off > 0; off >>= 1) v += __shfl_xor(v, off, 64);
    return v;
}

// ACT: 0=none, 2=leaky(0.01), 3=sigmoid.  GUMBEL: fuse w += log(-log(u+1e-30))
template <int ACT, int GUMBEL>
__global__ __launch_bounds__(256) void gemm_f32(
    const float* __restrict__ A, const float* __restrict__ B,
    const float* __restrict__ bias, const float* __restrict__ noise,
    float* __restrict__ C, int M, int N, int K)
{
    __shared__ float As[GBK][LDP];  // k-major: As[k][m]
    __shared__ float Bs[GBK][LDP];  // Bs[k][n]
    const int tid = threadIdx.x;
    const int tx = tid & 15;
    const int ty = tid >> 4;
    const int m0 = blockIdx.y * TILE;
    const int n0 = blockIdx.x * TILE;

    float acc[4][4] = {};

    for (int k0 = 0; k0 < K; k0 += GBK) {
#pragma unroll
        for (int t = 0; t < 4; t++) {           // A tile: 64 m x 16 k
            int idx = tid + t * 256;
            int ml = idx >> 4, kk = idx & 15;
            int gm = m0 + ml, gk = k0 + kk;
            As[kk][ml] = (gm < M && gk < K) ? A[(size_t)gm * K + gk] : 0.0f;
        }
#pragma unroll
        for (int t = 0; t < 4; t++) {           // B tile: 16 k x 64 n
            int idx = tid + t * 256;
            int kb = idx >> 6, nl = idx & 63;
            int gk = k0 + kb, gn = n0 + nl;
            Bs[kb][nl] = (gk < K && gn < N) ? B[(size_t)gk * N + gn] : 0.0f;
        }
        __syncthreads();
#pragma unroll
        for (int kk = 0; kk < GBK; kk++) {
            float4 av = *(const float4*)&As[kk][ty * 4];
            float4 bv = *(const float4*)&Bs[kk][tx * 4];
            float a_[4] = {av.x, av.y, av.z, av.w};
            float b_[4] = {bv.x, bv.y, bv.z, bv.w};
#pragma unroll
            for (int i = 0; i < 4; i++)
#pragma unroll
                for (int j = 0; j < 4; j++)
                    acc[i][j] = fmaf(a_[i], b_[j], acc[i][j]);
        }
        __syncthreads();
    }

#pragma unroll
    for (int i = 0; i < 4; i++) {
        int gm = m0 + ty * 4 + i;
        if (gm >= M) continue;
#pragma unroll
        for (int j = 0; j < 4; j++) {
            int gn = n0 + tx * 4 + j;
            if (gn >= N) continue;
            float v = acc[i][j] + bias[gn];
            if (GUMBEL) {
                float u = noise[(size_t)gm * N + gn] + 1e-30f;  // (1-1e-30)==1 in fp32/fp64
                v += logf(-logf(u));
            }
            if (ACT == 2) v = (v > 0.0f) ? v : 0.01f * v;
            else if (ACT == 3) v = 1.0f / (1.0f + expf(-v));
            C[(size_t)gm * N + gn] = v;
        }
    }
}

// ---- BatchNorm (training-mode batch stats over B=4096, 512 columns) --------
__global__ __launch_bounds__(256) void bn_stats_kernel(
    const float* __restrict__ h, float* __restrict__ csum, float* __restrict__ csq)
{
    int c = threadIdx.x;               // 256 threads cover 512 cols in 2 strides
    int r0 = blockIdx.x * 32;          // 128 blocks x 32 rows
    float s0 = 0, q0 = 0, s1 = 0, q1 = 0;
    for (int r = 0; r < 32; r++) {
        const float* row = h + (size_t)(r0 + r) * 512;
        float a = row[c], b = row[c + 256];
        s0 += a; q0 = fmaf(a, a, q0);
        s1 += b; q1 = fmaf(b, b, q1);
    }
    atomicAdd(&csum[c], s0);       atomicAdd(&csq[c], q0);
    atomicAdd(&csum[c + 256], s1); atomicAdd(&csq[c + 256], q1);
}

__global__ __launch_bounds__(256) void bn_apply_relu_kernel(
    float* __restrict__ h, const float* __restrict__ csum, const float* __restrict__ csq,
    const float* __restrict__ g, const float* __restrict__ b)
{
    int idx = blockIdx.x * 256 + threadIdx.x;   // 4096*512 elements
    int c = idx & 511;
    float mean = csum[c] * (1.0f / 4096.0f);
    float var  = csq[c] * (1.0f / 4096.0f) - mean * mean;
    float inv  = rsqrtf(var + 1e-5f);
    float v = (h[idx] - mean) * inv * g[c] + b[c];
    h[idx] = fmaxf(v, 0.0f);
}

__global__ void zero_kernel(float* p, int n) {
    int i = blockIdx.x * 256 + threadIdx.x;
    if (i < n) p[i] = 0.0f;
}

// ---- continuous top-k (K=50, T=0.1) + xm = x*subset, in place over w -------
// one 256-thread block per row; 20 elements/thread in registers (5120 >= 5000)
__global__ __launch_bounds__(256) void topk_xm_kernel(
    float* __restrict__ wx, const float* __restrict__ x, int N)
{
    __shared__ float smx[4], sms[4];
    const int row = blockIdx.x;
    const int tid = threadIdx.x;
    float* wr = wx + (size_t)row * N;
    const float* xr = x + (size_t)row * N;

    float w[20], oh[20], sub[20];
#pragma unroll
    for (int i = 0; i < 20; i++) {
        int idx = tid + (i << 8);
        w[i] = (idx < N) ? wr[idx] : -3.0e38f;
        oh[i] = 0.0f;
        sub[i] = 0.0f;
    }

    for (int it = 0; it < 50; it++) {
        // w += log(max(1 - onehot_prev, 1e-30)); track local max
        float lm = -3.0e38f;
#pragma unroll
        for (int i = 0; i < 20; i++) {
            w[i] += __logf(fmaxf(1.0f - oh[i], 1e-30f));
            lm = fmaxf(lm, w[i]);
        }
        lm = wave_max64(lm);
        if ((tid & 63) == 0) smx[tid >> 6] = lm;
        __syncthreads();
        float m = fmaxf(fmaxf(smx[0], smx[1]), fmaxf(smx[2], smx[3]));

        // softmax((w - m)/T)
        float ls = 0.0f;
#pragma unroll
        for (int i = 0; i < 20; i++) {
            float e = __expf((w[i] - m) * 10.0f);   // 1/T = 10
            oh[i] = e;
            ls += e;
        }
        ls = wave_sum64(ls);
        if ((tid & 63) == 0) sms[tid >> 6] = ls;
        __syncthreads();
        float rs = 1.0f / (sms[0] + sms[1] + sms[2] + sms[3]);
#pragma unroll
        for (int i = 0; i < 20; i++) {
            oh[i] *= rs;
            sub[i] += oh[i];
        }
    }

#pragma unroll
    for (int i = 0; i < 20; i++) {
        int idx = tid + (i << 8);
        if (idx < N) wr[idx] = xr[idx] * sub[i];
    }
}

__global__ void reparam_kernel(const float* __restrict__ mu, const float* __restrict__ lv,
                               const float* __restrict__ eps, float* __restrict__ z, int n)
{
    int i = blockIdx.x * 256 + threadIdx.x;
    if (i < n) z[i] = fmaf(eps[i], expf(0.5f * lv[i]), mu[i]);
}

// ---------------------------------------------------------------------------
extern "C" void kernel_launch(void* const* d_in, const int* in_sizes, int n_in,
                              void* d_out, int out_size, void* d_ws, size_t ws_size,
                              hipStream_t stream)
{
    const float* x      = (const float*)d_in[0];
    const float* noise  = (const float*)d_in[1];
    const float* epsv   = (const float*)d_in[2];
    const float* wc_w1  = (const float*)d_in[3];
    const float* wc_b1  = (const float*)d_in[4];
    const float* bn_g   = (const float*)d_in[5];
    const float* bn_b   = (const float*)d_in[6];
    const float* wc_w2  = (const float*)d_in[7];
    const float* wc_b2  = (const float*)d_in[8];
    const float* enc_w1 = (const float*)d_in[9];
    const float* enc_b1 = (const float*)d_in[10];
    const float* enc_w2 = (const float*)d_in[11];
    const float* enc_b2 = (const float*)d_in[12];
    const float* enc_w3 = (const float*)d_in[13];
    const float* enc_b3 = (const float*)d_in[14];
    const float* enc_w4 = (const float*)d_in[15];
    const float* enc_b4 = (const float*)d_in[16];
    const float* mean_w = (const float*)d_in[17];
    const float* mean_b = (const float*)d_in[18];
    const float* lv_w   = (const float*)d_in[19];
    const float* lv_b   = (const float*)d_in[20];
    const float* dec_w1 = (const float*)d_in[21];
    const float* dec_b1 = (const float*)d_in[22];
    const float* dec_w2 = (const float*)d_in[23];
    const float* dec_b2 = (const float*)d_in[24];

    const int B = 4096, D = 5000, H = 512, Z = 64;

    float* out  = (float*)d_out;
    float* mu_x = out;                        // 4096*5000 — also scratch for w/xm (written last)
    float* mu_l = out + (size_t)B * D;        // 4096*64
    float* lv_l = mu_l + (size_t)B * Z;       // 4096*64

    float* ws     = (float*)d_ws;
    float* buf_w  = mu_x;                     // w then xm, lives in out[0] region
    float* buf_h  = ws;                       // 4096*512
    float* buf_e1 = buf_h + (size_t)B * H;    // 4096*1024 (e1, later d)
    float* buf_e2 = buf_e1 + (size_t)B * 2 * H; // 4096*512 (e2, later e4)
    float* buf_e3 = buf_e2 + (size_t)B * H;   // 4096*512
    float* buf_z  = buf_e3 + (size_t)B * H;   // 4096*64
    float* csum   = buf_z + (size_t)B * Z;    // 512
    float* csq    = csum + 512;               // 512

    // weight_creator: h = x@wc_w1+b1 ; BN(train) ; ReLU ; w = h@wc_w2+b2 + gumbel
    zero_kernel<<<4, 256, 0, stream>>>(csum, 1024);
    gemm_f32<0, 0><<<dim3(H / 64, B / 64), 256, 0, stream>>>(x, wc_w1, wc_b1, nullptr, buf_h, B, H, D);
    bn_stats_kernel<<<128, 256, 0, stream>>>(buf_h, csum, csq);
    bn_apply_relu_kernel<<<B * H / 256, 256, 0, stream>>>(buf_h, csum, csq, bn_g, bn_b);
    gemm_f32<0, 1><<<dim3((D + 63) / 64, B / 64), 256, 0, stream>>>(buf_h, wc_w2, wc_b2, noise, buf_w, B, D, H);

    // continuous top-k + mask
    topk_xm_kernel<<<B, 256, 0, stream>>>(buf_w, x, D);

    // encoder
    gemm_f32<2, 0><<<dim3(2 * H / 64, B / 64), 256, 0, stream>>>(buf_w, enc_w1, enc_b1, nullptr, buf_e1, B, 2 * H, D);
    gemm_f32<2, 0><<<dim3(H / 64, B / 64), 256, 0, stream>>>(buf_e1, enc_w2, enc_b2, nullptr, buf_e2, B, H, 2 * H);
    gemm_f32<2, 0><<<dim3(H / 64, B / 64), 256, 0, stream>>>(buf_e2, enc_w3, enc_b3, nullptr, buf_e3, B, H, H);
    gemm_f32<2, 0><<<dim3(H / 64, B / 64), 256, 0, stream>>>(buf_e3, enc_w4, enc_b4, nullptr, buf_e2, B, H, H);

    // latent heads + reparameterize
    gemm_f32<0, 0><<<dim3(1, B / 64), 256, 0, stream>>>(buf_e2, mean_w, mean_b, nullptr, mu_l, B, Z, H);
    gemm_f32<0, 0><<<dim3(1, B / 64), 256, 0, stream>>>(buf_e2, lv_w, lv_b, nullptr, lv_l, B, Z, H);
    reparam_kernel<<<B * Z / 256, 256, 0, stream>>>(mu_l, lv_l, epsv, buf_z, B * Z);

    // decoder
    gemm_f32<2, 0><<<dim3(2 * H / 64, B / 64), 256, 0, stream>>>(buf_z, dec_w1, dec_b1, nullptr, buf_e1, B, 2 * H, Z);
    gemm_f32<3, 0><<<dim3((D + 63) / 64, B / 64), 256, 0, stream>>>(buf_e1, dec_w2, dec_b2, nullptr, mu_x, B, D, 2 * H);
}

// Round 2
// 1658.209 us; speedup vs baseline: 2.8941x; 2.8941x over previous
//
#include <hip/hip_runtime.h>
#include <math.h>

// ---------------------------------------------------------------------------
// VAE_Gumbel: B=4096, D=5000, H=512, Z=64
// Round 2: bf16 MFMA GEMMs (split-bf16 for the two GEMMs upstream of top-k)
// out = [mu_x (4096x5000), mu_latent (4096x64), logvar_latent (4096x64)]
// ---------------------------------------------------------------------------

typedef __attribute__((ext_vector_type(8))) short bf16x8;
typedef __attribute__((ext_vector_type(4))) float f32x4;

__device__ __forceinline__ short f2bf(float f) {  // RNE
    unsigned u = __builtin_bit_cast(unsigned, f);
    u += 0x7FFFu + ((u >> 16) & 1u);
    return (short)(u >> 16);
}
__device__ __forceinline__ float bf2f(short s) {
    unsigned u = ((unsigned)(unsigned short)s) << 16;
    return __builtin_bit_cast(float, u);
}

__device__ __forceinline__ float wave_max64(float v) {
#pragma unroll
    for (int off = 32; off > 0; off >>= 1) v = fmaxf(v, __shfl_xor(v, off, 64));
    return v;
}
__device__ __forceinline__ float wave_sum64(float v) {
#pragma unroll
    for (int off = 32; off > 0; off >>= 1) v += __shfl_xor(v, off, 64);
    return v;
}

// ======================= MFMA GEMM =========================================
// C[M,N] = A[M,Kp] @ Bt[Np,Kp]^T  (A, Bt bf16 row-major, contiguous Kp)
// 128x128 block tile, BK=32, 256 threads (4 waves, each 64x64).
// SPLIT: A/B given as hi+lo bf16 pairs; acc = hi*hi + hi*lo + lo*hi.
// ATOMIC: split-K accumulation via atomicAdd (no bias/act).
// ACT: 0 none, 2 leaky, 3 sigmoid. GUMBEL: +log(-log(noise+1e-30)).
template <int SPLIT, int ACT, int GUMBEL, int ATOMIC, int OUT_BF16>
__global__ __launch_bounds__(256, 2) void gemm_mfma(
    const short* __restrict__ Ah, const short* __restrict__ Al,
    const short* __restrict__ Bth, const short* __restrict__ Btl,
    const float* __restrict__ bias, const float* __restrict__ noise,
    float* __restrict__ Cf, short* __restrict__ Cb, int N, int Kp)
{
    __shared__ short lds[(SPLIT ? 4 : 2) * 4096];  // As | Bs | (Asl | Bsl)
    short* As = lds;
    short* Bs = lds + 4096;

    const int tid = threadIdx.x;
    const int m0 = blockIdx.y << 7;
    const int n0 = blockIdx.x << 7;

    const int steps = Kp >> 5;
    const int per = (steps + gridDim.z - 1) / gridDim.z;
    const int s_begin = blockIdx.z * per;
    const int s_end = min(steps, s_begin + per);

    // staging: chunk c in [0,512): row r=c>>2 (of 128), 16B part p=c&3; this
    // thread does c=tid and c=tid+256 (row r+64, same p) for A and Bt.
    const int r = tid >> 2;
    const int p = tid & 3;
    const size_t a_off = (size_t)(m0 + r) * Kp + p * 8;
    const size_t b_off = (size_t)(n0 + r) * Kp + p * 8;
    const size_t row64 = (size_t)64 * Kp;
    short* As_d1 = As + tid * 8;
    short* As_d2 = As + (tid + 256) * 8;
    short* Bs_d1 = Bs + tid * 8;
    short* Bs_d2 = Bs + (tid + 256) * 8;

    const int lane = tid & 63;
    const int wid = tid >> 6;
    const int wm = (wid >> 1) << 6;
    const int wn = (wid & 1) << 6;
    const int fr = lane & 15;
    const int quad = lane >> 4;

    f32x4 acc[4][4];
#pragma unroll
    for (int i = 0; i < 4; i++)
#pragma unroll
        for (int j = 0; j < 4; j++)
            acc[i][j] = (f32x4){0.f, 0.f, 0.f, 0.f};

    for (int s = s_begin; s < s_end; s++) {
        const size_t k0 = (size_t)s << 5;
        uint4 a1 = *(const uint4*)(Ah + a_off + k0);
        uint4 a2 = *(const uint4*)(Ah + a_off + row64 + k0);
        uint4 b1 = *(const uint4*)(Bth + b_off + k0);
        uint4 b2 = *(const uint4*)(Bth + b_off + row64 + k0);
        uint4 a3, a4, b3, b4;
        if (SPLIT) {
            a3 = *(const uint4*)(Al + a_off + k0);
            a4 = *(const uint4*)(Al + a_off + row64 + k0);
            b3 = *(const uint4*)(Btl + b_off + k0);
            b4 = *(const uint4*)(Btl + b_off + row64 + k0);
        }
        __syncthreads();
        *(uint4*)As_d1 = a1; *(uint4*)As_d2 = a2;
        *(uint4*)Bs_d1 = b1; *(uint4*)Bs_d2 = b2;
        if (SPLIT) {
            *(uint4*)(As_d1 + 8192) = a3; *(uint4*)(As_d2 + 8192) = a4;
            *(uint4*)(Bs_d1 + 8192) = b3; *(uint4*)(Bs_d2 + 8192) = b4;
        }
        __syncthreads();

        bf16x8 af[4], bf[4];
#pragma unroll
        for (int i = 0; i < 4; i++)
            af[i] = *(const bf16x8*)(As + ((wm + i * 16 + fr) << 5) + (quad << 3));
#pragma unroll
        for (int j = 0; j < 4; j++)
            bf[j] = *(const bf16x8*)(Bs + ((wn + j * 16 + fr) << 5) + (quad << 3));
#pragma unroll
        for (int i = 0; i < 4; i++)
#pragma unroll
            for (int j = 0; j < 4; j++)
                acc[i][j] = __builtin_amdgcn_mfma_f32_16x16x32_bf16(af[i], bf[j], acc[i][j], 0, 0, 0);
        if (SPLIT) {
            bf16x8 al[4], bl[4];
#pragma unroll
            for (int i = 0; i < 4; i++)
                al[i] = *(const bf16x8*)(As + 8192 + ((wm + i * 16 + fr) << 5) + (quad << 3));
#pragma unroll
            for (int j = 0; j < 4; j++)
                bl[j] = *(const bf16x8*)(Bs + 8192 + ((wn + j * 16 + fr) << 5) + (quad << 3));
#pragma unroll
            for (int i = 0; i < 4; i++)
#pragma unroll
                for (int j = 0; j < 4; j++) {
                    acc[i][j] = __builtin_amdgcn_mfma_f32_16x16x32_bf16(af[i], bl[j], acc[i][j], 0, 0, 0);
                    acc[i][j] = __builtin_amdgcn_mfma_f32_16x16x32_bf16(al[i], bf[j], acc[i][j], 0, 0, 0);
                }
        }
    }

    // epilogue: D row = quad*4+rr, col = fr (m89/m91-verified layout)
#pragma unroll
    for (int i = 0; i < 4; i++) {
#pragma unroll
        for (int j = 0; j < 4; j++) {
#pragma unroll
            for (int rr = 0; rr < 4; rr++) {
                int gm = m0 + wm + i * 16 + quad * 4 + rr;
                int gn = n0 + wn + j * 16 + fr;
                if (gn < N) {
                    size_t o = (size_t)gm * N + gn;
                    float v = acc[i][j][rr];
                    if (ATOMIC) {
                        atomicAdd(Cf + o, v);
                    } else {
                        v += bias[gn];
                        if (GUMBEL) v += logf(-logf(noise[o] + 1e-30f));
                        if (ACT == 2) v = v > 0.f ? v : 0.01f * v;
                        if (ACT == 3) v = 1.f / (1.f + expf(-v));
                        if (OUT_BF16) Cb[o] = f2bf(v); else Cf[o] = v;
                    }
                }
            }
        }
    }
}

// ======================= fp32 vector GEMM (small shapes) ===================
#define TILE 64
#define GBK  16
#define LDP  (TILE + 4)

template <int ACT, int OB>
__global__ __launch_bounds__(256) void gemm_f32(
    const float* __restrict__ A, const float* __restrict__ B,
    const float* __restrict__ bias, float* __restrict__ Cf, short* __restrict__ Cb,
    int M, int N, int K)
{
    __shared__ float As[GBK][LDP];
    __shared__ float Bs[GBK][LDP];
    const int tid = threadIdx.x;
    const int tx = tid & 15;
    const int ty = tid >> 4;
    const int m0 = blockIdx.y * TILE;
    const int n0 = blockIdx.x * TILE;

    float acc[4][4] = {};

    for (int k0 = 0; k0 < K; k0 += GBK) {
#pragma unroll
        for (int t = 0; t < 4; t++) {
            int idx = tid + t * 256;
            int ml = idx >> 4, kk = idx & 15;
            int gm = m0 + ml, gk = k0 + kk;
            As[kk][ml] = (gm < M && gk < K) ? A[(size_t)gm * K + gk] : 0.0f;
        }
#pragma unroll
        for (int t = 0; t < 4; t++) {
            int idx = tid + t * 256;
            int kb = idx >> 6, nl = idx & 63;
            int gk = k0 + kb, gn = n0 + nl;
            Bs[kb][nl] = (gk < K && gn < N) ? B[(size_t)gk * N + gn] : 0.0f;
        }
        __syncthreads();
#pragma unroll
        for (int kk = 0; kk < GBK; kk++) {
            float4 av = *(const float4*)&As[kk][ty * 4];
            float4 bv = *(const float4*)&Bs[kk][tx * 4];
            float a_[4] = {av.x, av.y, av.z, av.w};
            float b_[4] = {bv.x, bv.y, bv.z, bv.w};
#pragma unroll
            for (int i = 0; i < 4; i++)
#pragma unroll
                for (int j = 0; j < 4; j++)
                    acc[i][j] = fmaf(a_[i], b_[j], acc[i][j]);
        }
        __syncthreads();
    }

#pragma unroll
    for (int i = 0; i < 4; i++) {
        int gm = m0 + ty * 4 + i;
        if (gm >= M) continue;
#pragma unroll
        for (int j = 0; j < 4; j++) {
            int gn = n0 + tx * 4 + j;
            if (gn >= N) continue;
            float v = acc[i][j] + bias[gn];
            if (ACT == 2) v = (v > 0.0f) ? v : 0.01f * v;
            if (OB) Cb[(size_t)gm * N + gn] = f2bf(v);
            else    Cf[(size_t)gm * N + gn] = v;
        }
    }
}

// ======================= packs / BN / misc =================================
// A pack with split: in fp32 [M,K] -> hi/lo bf16 [M,Kp] (zero pad)
__global__ __launch_bounds__(256) void pack_a_split(
    const float* __restrict__ in, short* __restrict__ hi, short* __restrict__ lo,
    int K, int Kp)
{
    int k = blockIdx.x * 256 + threadIdx.x;
    if (k >= Kp) return;
    int m = blockIdx.y;
    float v = (k < K) ? in[(size_t)m * K + k] : 0.f;
    short h = f2bf(v);
    size_t o = (size_t)m * Kp + k;
    hi[o] = h;
    lo[o] = f2bf(v - bf2f(h));
}

// B^T pack: in fp32 [K,N] -> bf16 [Np,Kp] transposed (zero pad)
template <int SPLITB>
__global__ __launch_bounds__(1024) void pack_bt(
    const float* __restrict__ B, short* __restrict__ bth, short* __restrict__ btl,
    int K, int N, int Kp, int Np)
{
    __shared__ float t[32][33];
    int k0 = blockIdx.x * 32, n0 = blockIdx.y * 32;
    int tx = threadIdx.x, ty = threadIdx.y;
    int gk = k0 + ty, gn = n0 + tx;
    t[ty][tx] = (gk < K && gn < N) ? B[(size_t)gk * N + gn] : 0.f;
    __syncthreads();
    int on = n0 + ty, ok = k0 + tx;
    if (on < Np && ok < Kp) {
        float v = t[tx][ty];
        short h = f2bf(v);
        size_t o = (size_t)on * Kp + ok;
        bth[o] = h;
        if (SPLITB) btl[o] = f2bf(v - bf2f(h));
    }
}

__global__ __launch_bounds__(256) void bn_stats_kernel(
    const float* __restrict__ h, float* __restrict__ csum, float* __restrict__ csq)
{
    int c = threadIdx.x;
    int r0 = blockIdx.x * 32;
    float s0 = 0, q0 = 0, s1 = 0, q1 = 0;
    for (int r = 0; r < 32; r++) {
        const float* row = h + (size_t)(r0 + r) * 512;
        float a = row[c], b = row[c + 256];
        s0 += a; q0 = fmaf(a, a, q0);
        s1 += b; q1 = fmaf(b, b, q1);
    }
    atomicAdd(&csum[c], s0);       atomicAdd(&csq[c], q0);
    atomicAdd(&csum[c + 256], s1); atomicAdd(&csq[c + 256], q1);
}

// BN(train) + ReLU, output split hi/lo bf16 (feeds SPLIT w-gemm)
__global__ __launch_bounds__(256) void bn_apply_split(
    const float* __restrict__ h, const float* __restrict__ csum, const float* __restrict__ csq,
    const float* __restrict__ g, const float* __restrict__ b,
    short* __restrict__ hh, short* __restrict__ hl)
{
    int idx = blockIdx.x * 256 + threadIdx.x;
    int c = idx & 511;
    float mean = csum[c] * (1.0f / 4096.0f);
    float var  = csq[c] * (1.0f / 4096.0f) - mean * mean;
    float inv  = rsqrtf(var + 1e-5f);
    float v = (h[idx] - mean) * inv * g[c] + b[c];
    v = fmaxf(v, 0.0f);
    short hi = f2bf(v);
    hh[idx] = hi;
    hl[idx] = f2bf(v - bf2f(hi));
}

template <int OB>
__global__ __launch_bounds__(256) void bias_act(
    const float* __restrict__ in, const float* __restrict__ bias,
    float* __restrict__ outf, short* __restrict__ outb, int mask, int total)
{
    int i = blockIdx.x * 256 + threadIdx.x;
    if (i < total) {
        float v = in[i] + bias[i & mask];
        v = v > 0.f ? v : 0.01f * v;
        if (OB) outb[i] = f2bf(v); else outf[i] = v;
    }
}

__global__ void zero_kernel(float* p, int n) {
    int i = blockIdx.x * 256 + threadIdx.x;
    if (i < n) p[i] = 0.0f;
}

// ---- continuous top-k (K=50, T=0.1); writes xm as bf16 [4096,5024] --------
__global__ __launch_bounds__(256) void topk_xm_kernel(
    const float* __restrict__ wsrc, const float* __restrict__ x,
    short* __restrict__ xm, int N)
{
    __shared__ float smx[4], sms[4];
    const int row = blockIdx.x;
    const int tid = threadIdx.x;
    const float* wr = wsrc + (size_t)row * N;
    const float* xr = x + (size_t)row * N;
    short* xmr = xm + (size_t)row * 5024;

    float w[20], oh[20], sub[20];
#pragma unroll
    for (int i = 0; i < 20; i++) {
        int idx = tid + (i << 8);
        w[i] = (idx < N) ? wr[idx] : -3.0e38f;
        oh[i] = 0.0f;
        sub[i] = 0.0f;
    }

    for (int it = 0; it < 50; it++) {
        float lm = -3.0e38f;
#pragma unroll
        for (int i = 0; i < 20; i++) {
            w[i] += __logf(fmaxf(1.0f - oh[i], 1e-30f));
            lm = fmaxf(lm, w[i]);
        }
        lm = wave_max64(lm);
        if ((tid & 63) == 0) smx[tid >> 6] = lm;
        __syncthreads();
        float m = fmaxf(fmaxf(smx[0], smx[1]), fmaxf(smx[2], smx[3]));

        float ls = 0.0f;
#pragma unroll
        for (int i = 0; i < 20; i++) {
            float e = __expf((w[i] - m) * 10.0f);
            oh[i] = e;
            ls += e;
        }
        ls = wave_sum64(ls);
        if ((tid & 63) == 0) sms[tid >> 6] = ls;
        __syncthreads();
        float rs = 1.0f / (sms[0] + sms[1] + sms[2] + sms[3]);
#pragma unroll
        for (int i = 0; i < 20; i++) {
            oh[i] *= rs;
            sub[i] += oh[i];
        }
    }

#pragma unroll
    for (int i = 0; i < 20; i++) {
        int idx = tid + (i << 8);
        if (idx < 5024) xmr[idx] = (idx < N) ? f2bf(xr[idx] * sub[i]) : (short)0;
    }
}

__global__ void reparam_kernel(const float* __restrict__ mu, const float* __restrict__ lv,
                               const float* __restrict__ eps, float* __restrict__ z, int n)
{
    int i = blockIdx.x * 256 + threadIdx.x;
    if (i < n) z[i] = fmaf(eps[i], expf(0.5f * lv[i]), mu[i]);
}

// ---------------------------------------------------------------------------
extern "C" void kernel_launch(void* const* d_in, const int* in_sizes, int n_in,
                              void* d_out, int out_size, void* d_ws, size_t ws_size,
                              hipStream_t stream)
{
    const float* x      = (const float*)d_in[0];
    const float* noise  = (const float*)d_in[1];
    const float* epsv   = (const float*)d_in[2];
    const float* wc_w1  = (const float*)d_in[3];
    // d_in[4] wc_b1: absorbed by BatchNorm (train mode) — unused
    const float* bn_g   = (const float*)d_in[5];
    const float* bn_b   = (const float*)d_in[6];
    const float* wc_w2  = (const float*)d_in[7];
    const float* wc_b2  = (const float*)d_in[8];
    const float* enc_w1 = (const float*)d_in[9];
    const float* enc_b1 = (const float*)d_in[10];
    const float* enc_w2 = (const float*)d_in[11];
    const float* enc_b2 = (const float*)d_in[12];
    const float* enc_w3 = (const float*)d_in[13];
    const float* enc_b3 = (const float*)d_in[14];
    const float* enc_w4 = (const float*)d_in[15];
    const float* enc_b4 = (const float*)d_in[16];
    const float* mean_w = (const float*)d_in[17];
    const float* mean_b = (const float*)d_in[18];
    const float* lv_w   = (const float*)d_in[19];
    const float* lv_b   = (const float*)d_in[20];
    const float* dec_w1 = (const float*)d_in[21];
    const float* dec_b1 = (const float*)d_in[22];
    const float* dec_w2 = (const float*)d_in[23];
    const float* dec_b2 = (const float*)d_in[24];

    const int B = 4096, D = 5000, H = 512, Z = 64;
    const int Dk = 5024;   // D padded to 32 (K pad)
    const int Dn = 5120;   // D padded to 128 (N pad for Bt rows)

    float* out  = (float*)d_out;
    float* mu_x = out;                        // also holds w until topk
    float* mu_l = out + (size_t)B * D;
    float* lv_l = mu_l + (size_t)B * Z;
    float* w_buf = mu_x;

    // ---- workspace layout (bytes, 256-aligned) ----
    char* base = (char*)d_ws;
    size_t off = 0;
    auto alloc = [&](size_t bytes) { size_t r = off; off += (bytes + 255) & ~(size_t)255; return r; };
    const size_t XS = (size_t)B * Dk;             // 4096*5024
    size_t o_xhi   = alloc(XS * 2);               // x_hi  -> later xm_bf16
    size_t o_xlo   = alloc(XS * 2);               // x_lo  -> later e1_acc | e1_bf16 | e2_acc
    size_t o_bufh  = alloc((size_t)B * H * 4);
    size_t o_hhi   = alloc((size_t)B * H * 2);
    size_t o_hlo   = alloc((size_t)B * H * 2);
    size_t o_e2b   = alloc((size_t)B * H * 2);
    size_t o_e3a   = alloc((size_t)B * H * 4);
    size_t o_e3b   = alloc((size_t)B * H * 2);
    size_t o_e4    = alloc((size_t)B * H * 4);
    size_t o_z     = alloc((size_t)B * Z * 4);
    size_t o_dbf   = alloc((size_t)B * 2 * H * 2);
    size_t o_csum  = alloc(512 * 4);
    size_t o_csq   = alloc(512 * 4);
    size_t o_w1th  = alloc((size_t)H * Dk * 2);
    size_t o_w1tl  = alloc((size_t)H * Dk * 2);
    size_t o_w2th  = alloc((size_t)Dn * H * 2);
    size_t o_w2tl  = alloc((size_t)Dn * H * 2);
    size_t o_e1wt  = alloc((size_t)(2 * H) * Dk * 2);
    size_t o_e2wt  = alloc((size_t)H * (2 * H) * 2);
    size_t o_e3wt  = alloc((size_t)H * H * 2);
    size_t o_e4wt  = alloc((size_t)H * H * 2);
    size_t o_d2wt  = alloc((size_t)Dn * (2 * H) * 2);

    short* x_hi  = (short*)(base + o_xhi);
    short* x_lo  = (short*)(base + o_xlo);
    short* xm_bf = (short*)(base + o_xhi);                    // alias (x_hi dead)
    float* e1_acc = (float*)(base + o_xlo);                   // alias (x_lo dead)
    short* e1_bf  = (short*)(base + o_xlo + (size_t)B * 2 * H * 4);
    float* e2_acc = (float*)(base + o_xlo + (size_t)B * 2 * H * 4 + (size_t)B * 2 * H * 2);
    float* buf_h = (float*)(base + o_bufh);
    short* h_hi  = (short*)(base + o_hhi);
    short* h_lo  = (short*)(base + o_hlo);
    short* e2_bf = (short*)(base + o_e2b);
    float* e3_acc = (float*)(base + o_e3a);
    short* e3_bf = (short*)(base + o_e3b);
    float* e4    = (float*)(base + o_e4);
    float* zbuf  = (float*)(base + o_z);
    short* d_bf  = (short*)(base + o_dbf);
    float* csum  = (float*)(base + o_csum);
    float* csq   = (float*)(base + o_csq);
    short* w1t_h = (short*)(base + o_w1th);
    short* w1t_l = (short*)(base + o_w1tl);
    short* w2t_h = (short*)(base + o_w2th);
    short* w2t_l = (short*)(base + o_w2tl);
    short* e1wt  = (short*)(base + o_e1wt);
    short* e2wt  = (short*)(base + o_e2wt);
    short* e3wt  = (short*)(base + o_e3wt);
    short* e4wt  = (short*)(base + o_e4wt);
    short* d2wt  = (short*)(base + o_d2wt);

    dim3 tb(32, 32);

    // ---- packs ----
    pack_a_split<<<dim3((Dk + 255) / 256, B), 256, 0, stream>>>(x, x_hi, x_lo, D, Dk);
    pack_bt<1><<<dim3(Dk / 32, H / 32), tb, 0, stream>>>(wc_w1, w1t_h, w1t_l, D, H, Dk, H);
    pack_bt<1><<<dim3(H / 32, Dn / 32), tb, 0, stream>>>(wc_w2, w2t_h, w2t_l, H, D, H, Dn);
    pack_bt<0><<<dim3(Dk / 32, 2 * H / 32), tb, 0, stream>>>(enc_w1, e1wt, nullptr, D, 2 * H, Dk, 2 * H);
    pack_bt<0><<<dim3(2 * H / 32, H / 32), tb, 0, stream>>>(enc_w2, e2wt, nullptr, 2 * H, H, 2 * H, H);
    pack_bt<0><<<dim3(H / 32, H / 32), tb, 0, stream>>>(enc_w3, e3wt, nullptr, H, H, H, H);
    pack_bt<0><<<dim3(H / 32, H / 32), tb, 0, stream>>>(enc_w4, e4wt, nullptr, H, H, H, H);
    pack_bt<0><<<dim3(2 * H / 32, Dn / 32), tb, 0, stream>>>(dec_w2, d2wt, nullptr, 2 * H, D, 2 * H, Dn);

    // ---- weight_creator: h = x@wc_w1 (SPLIT, SK=4, atomic) ----
    zero_kernel<<<(B * H + 255) / 256, 256, 0, stream>>>(buf_h, B * H);
    zero_kernel<<<4, 256, 0, stream>>>(csum, 1024);  // csum+csq contiguous
    gemm_mfma<1, 0, 0, 1, 0><<<dim3(H / 128, B / 128, 4), 256, 0, stream>>>(
        x_hi, x_lo, w1t_h, w1t_l, nullptr, nullptr, buf_h, nullptr, H, Dk);
    bn_stats_kernel<<<128, 256, 0, stream>>>(buf_h, csum, csq);
    bn_apply_split<<<B * H / 256, 256, 0, stream>>>(buf_h, csum, csq, bn_g, bn_b, h_hi, h_lo);

    // ---- w = h@wc_w2 + b2 + gumbel (SPLIT, SK=1, fused epilogue) ----
    gemm_mfma<1, 0, 1, 0, 0><<<dim3((D + 127) / 128, B / 128, 1), 256, 0, stream>>>(
        h_hi, h_lo, w2t_h, w2t_l, wc_b2, noise, w_buf, nullptr, D, H);

    // ---- continuous top-k + mask -> xm bf16 ----
    topk_xm_kernel<<<B, 256, 0, stream>>>(w_buf, x, xm_bf, D);

    // ---- encoder ----
    zero_kernel<<<(B * 2 * H + 255) / 256, 256, 0, stream>>>(e1_acc, B * 2 * H);
    gemm_mfma<0, 0, 0, 1, 0><<<dim3(2 * H / 128, B / 128, 2), 256, 0, stream>>>(
        xm_bf, nullptr, e1wt, nullptr, nullptr, nullptr, e1_acc, nullptr, 2 * H, Dk);
    bias_act<1><<<(B * 2 * H + 255) / 256, 256, 0, stream>>>(e1_acc, enc_b1, nullptr, e1_bf, 2 * H - 1, B * 2 * H);

    zero_kernel<<<(B * H + 255) / 256, 256, 0, stream>>>(e2_acc, B * H);
    gemm_mfma<0, 0, 0, 1, 0><<<dim3(H / 128, B / 128, 4), 256, 0, stream>>>(
        e1_bf, nullptr, e2wt, nullptr, nullptr, nullptr, e2_acc, nullptr, H, 2 * H);
    bias_act<1><<<(B * H + 255) / 256, 256, 0, stream>>>(e2_acc, enc_b2, nullptr, e2_bf, H - 1, B * H);

    zero_kernel<<<(B * H + 255) / 256, 256, 0, stream>>>(e3_acc, B * H);
    gemm_mfma<0, 0, 0, 1, 0><<<dim3(H / 128, B / 128, 4), 256, 0, stream>>>(
        e2_bf, nullptr, e3wt, nullptr, nullptr, nullptr, e3_acc, nullptr, H, H);
    bias_act<1><<<(B * H + 255) / 256, 256, 0, stream>>>(e3_acc, enc_b3, nullptr, e3_bf, H - 1, B * H);

    zero_kernel<<<(B * H + 255) / 256, 256, 0, stream>>>(e4, B * H);
    gemm_mfma<0, 0, 0, 1, 0><<<dim3(H / 128, B / 128, 4), 256, 0, stream>>>(
        e3_bf, nullptr, e4wt, nullptr, nullptr, nullptr, e4, nullptr, H, H);
    bias_act<0><<<(B * H + 255) / 256, 256, 0, stream>>>(e4, enc_b4, e4, nullptr, H - 1, B * H);

    // ---- latent heads + reparameterize (fp32 vector, tiny) ----
    gemm_f32<0, 0><<<dim3(1, B / 64), 256, 0, stream>>>(e4, mean_w, mean_b, mu_l, nullptr, B, Z, H);
    gemm_f32<0, 0><<<dim3(1, B / 64), 256, 0, stream>>>(e4, lv_w, lv_b, lv_l, nullptr, B, Z, H);
    reparam_kernel<<<(B * Z + 255) / 256, 256, 0, stream>>>(mu_l, lv_l, epsv, zbuf, B * Z);

    // ---- decoder ----
    gemm_f32<2, 1><<<dim3(2 * H / 64, B / 64), 256, 0, stream>>>(zbuf, dec_w1, dec_b1, nullptr, d_bf, B, 2 * H, Z);
    gemm_mfma<0, 3, 0, 0, 0><<<dim3((D + 127) / 128, B / 128, 1), 256, 0, stream>>>(
        d_bf, nullptr, d2wt, nullptr, dec_b2, nullptr, mu_x, nullptr, D, 2 * H);
}

// Round 3
// 1531.658 us; speedup vs baseline: 3.1332x; 1.0826x over previous
//
#include <hip/hip_runtime.h>
#include <math.h>

// ---------------------------------------------------------------------------
// VAE_Gumbel: B=4096, D=5000, H=512, Z=64
// Round 3: sparse incremental continuous-top-k (active-set softmax)
// out = [mu_x (4096x5000), mu_latent (4096x64), logvar_latent (4096x64)]
// ---------------------------------------------------------------------------

typedef __attribute__((ext_vector_type(8))) short bf16x8;
typedef __attribute__((ext_vector_type(4))) float f32x4;

__device__ __forceinline__ short f2bf(float f) {  // RNE
    unsigned u = __builtin_bit_cast(unsigned, f);
    u += 0x7FFFu + ((u >> 16) & 1u);
    return (short)(u >> 16);
}
__device__ __forceinline__ float bf2f(short s) {
    unsigned u = ((unsigned)(unsigned short)s) << 16;
    return __builtin_bit_cast(float, u);
}

__device__ __forceinline__ float wave_max64(float v) {
#pragma unroll
    for (int off = 32; off > 0; off >>= 1) v = fmaxf(v, __shfl_xor(v, off, 64));
    return v;
}
__device__ __forceinline__ float wave_sum64(float v) {
#pragma unroll
    for (int off = 32; off > 0; off >>= 1) v += __shfl_xor(v, off, 64);
    return v;
}

// ======================= MFMA GEMM =========================================
// C[M,N] = A[M,Kp] @ Bt[Np,Kp]^T  (A, Bt bf16 row-major, contiguous Kp)
// 128x128 block tile, BK=32, 256 threads (4 waves, each 64x64).
// SPLIT: A/B given as hi+lo bf16 pairs; acc = hi*hi + hi*lo + lo*hi.
// ATOMIC: split-K accumulation via atomicAdd (no bias/act).
// ACT: 0 none, 2 leaky, 3 sigmoid. GUMBEL: +log(-log(noise+1e-30)).
template <int SPLIT, int ACT, int GUMBEL, int ATOMIC, int OUT_BF16>
__global__ __launch_bounds__(256, 2) void gemm_mfma(
    const short* __restrict__ Ah, const short* __restrict__ Al,
    const short* __restrict__ Bth, const short* __restrict__ Btl,
    const float* __restrict__ bias, const float* __restrict__ noise,
    float* __restrict__ Cf, short* __restrict__ Cb, int N, int Kp)
{
    __shared__ short lds[(SPLIT ? 4 : 2) * 4096];  // As | Bs | (Asl | Bsl)
    short* As = lds;
    short* Bs = lds + 4096;

    const int tid = threadIdx.x;
    const int m0 = blockIdx.y << 7;
    const int n0 = blockIdx.x << 7;

    const int steps = Kp >> 5;
    const int per = (steps + gridDim.z - 1) / gridDim.z;
    const int s_begin = blockIdx.z * per;
    const int s_end = min(steps, s_begin + per);

    const int r = tid >> 2;
    const int p = tid & 3;
    const size_t a_off = (size_t)(m0 + r) * Kp + p * 8;
    const size_t b_off = (size_t)(n0 + r) * Kp + p * 8;
    const size_t row64 = (size_t)64 * Kp;
    short* As_d1 = As + tid * 8;
    short* As_d2 = As + (tid + 256) * 8;
    short* Bs_d1 = Bs + tid * 8;
    short* Bs_d2 = Bs + (tid + 256) * 8;

    const int lane = tid & 63;
    const int wid = tid >> 6;
    const int wm = (wid >> 1) << 6;
    const int wn = (wid & 1) << 6;
    const int fr = lane & 15;
    const int quad = lane >> 4;

    f32x4 acc[4][4];
#pragma unroll
    for (int i = 0; i < 4; i++)
#pragma unroll
        for (int j = 0; j < 4; j++)
            acc[i][j] = (f32x4){0.f, 0.f, 0.f, 0.f};

    for (int s = s_begin; s < s_end; s++) {
        const size_t k0 = (size_t)s << 5;
        uint4 a1 = *(const uint4*)(Ah + a_off + k0);
        uint4 a2 = *(const uint4*)(Ah + a_off + row64 + k0);
        uint4 b1 = *(const uint4*)(Bth + b_off + k0);
        uint4 b2 = *(const uint4*)(Bth + b_off + row64 + k0);
        uint4 a3, a4, b3, b4;
        if (SPLIT) {
            a3 = *(const uint4*)(Al + a_off + k0);
            a4 = *(const uint4*)(Al + a_off + row64 + k0);
            b3 = *(const uint4*)(Btl + b_off + k0);
            b4 = *(const uint4*)(Btl + b_off + row64 + k0);
        }
        __syncthreads();
        *(uint4*)As_d1 = a1; *(uint4*)As_d2 = a2;
        *(uint4*)Bs_d1 = b1; *(uint4*)Bs_d2 = b2;
        if (SPLIT) {
            *(uint4*)(As_d1 + 8192) = a3; *(uint4*)(As_d2 + 8192) = a4;
            *(uint4*)(Bs_d1 + 8192) = b3; *(uint4*)(Bs_d2 + 8192) = b4;
        }
        __syncthreads();

        bf16x8 af[4], bf[4];
#pragma unroll
        for (int i = 0; i < 4; i++)
            af[i] = *(const bf16x8*)(As + ((wm + i * 16 + fr) << 5) + (quad << 3));
#pragma unroll
        for (int j = 0; j < 4; j++)
            bf[j] = *(const bf16x8*)(Bs + ((wn + j * 16 + fr) << 5) + (quad << 3));
#pragma unroll
        for (int i = 0; i < 4; i++)
#pragma unroll
            for (int j = 0; j < 4; j++)
                acc[i][j] = __builtin_amdgcn_mfma_f32_16x16x32_bf16(af[i], bf[j], acc[i][j], 0, 0, 0);
        if (SPLIT) {
            bf16x8 al[4], bl[4];
#pragma unroll
            for (int i = 0; i < 4; i++)
                al[i] = *(const bf16x8*)(As + 8192 + ((wm + i * 16 + fr) << 5) + (quad << 3));
#pragma unroll
            for (int j = 0; j < 4; j++)
                bl[j] = *(const bf16x8*)(Bs + 8192 + ((wn + j * 16 + fr) << 5) + (quad << 3));
#pragma unroll
            for (int i = 0; i < 4; i++)
#pragma unroll
                for (int j = 0; j < 4; j++) {
                    acc[i][j] = __builtin_amdgcn_mfma_f32_16x16x32_bf16(af[i], bl[j], acc[i][j], 0, 0, 0);
                    acc[i][j] = __builtin_amdgcn_mfma_f32_16x16x32_bf16(al[i], bf[j], acc[i][j], 0, 0, 0);
                }
        }
    }

    // epilogue: D row = quad*4+rr, col = fr (m89/m91-verified layout)
#pragma unroll
    for (int i = 0; i < 4; i++) {
#pragma unroll
        for (int j = 0; j < 4; j++) {
#pragma unroll
            for (int rr = 0; rr < 4; rr++) {
                int gm = m0 + wm + i * 16 + quad * 4 + rr;
                int gn = n0 + wn + j * 16 + fr;
                if (gn < N) {
                    size_t o = (size_t)gm * N + gn;
                    float v = acc[i][j][rr];
                    if (ATOMIC) {
                        atomicAdd(Cf + o, v);
                    } else {
                        v += bias[gn];
                        if (GUMBEL) v += logf(-logf(noise[o] + 1e-30f));
                        if (ACT == 2) v = v > 0.f ? v : 0.01f * v;
                        if (ACT == 3) v = 1.f / (1.f + expf(-v));
                        if (OUT_BF16) Cb[o] = f2bf(v); else Cf[o] = v;
                    }
                }
            }
        }
    }
}

// ======================= fp32 vector GEMM (small shapes) ===================
#define TILE 64
#define GBK  16
#define LDP  (TILE + 4)

template <int ACT, int OB>
__global__ __launch_bounds__(256) void gemm_f32(
    const float* __restrict__ A, const float* __restrict__ B,
    const float* __restrict__ bias, float* __restrict__ Cf, short* __restrict__ Cb,
    int M, int N, int K)
{
    __shared__ float As[GBK][LDP];
    __shared__ float Bs[GBK][LDP];
    const int tid = threadIdx.x;
    const int tx = tid & 15;
    const int ty = tid >> 4;
    const int m0 = blockIdx.y * TILE;
    const int n0 = blockIdx.x * TILE;

    float acc[4][4] = {};

    for (int k0 = 0; k0 < K; k0 += GBK) {
#pragma unroll
        for (int t = 0; t < 4; t++) {
            int idx = tid + t * 256;
            int ml = idx >> 4, kk = idx & 15;
            int gm = m0 + ml, gk = k0 + kk;
            As[kk][ml] = (gm < M && gk < K) ? A[(size_t)gm * K + gk] : 0.0f;
        }
#pragma unroll
        for (int t = 0; t < 4; t++) {
            int idx = tid + t * 256;
            int kb = idx >> 6, nl = idx & 63;
            int gk = k0 + kb, gn = n0 + nl;
            Bs[kb][nl] = (gk < K && gn < N) ? B[(size_t)gk * N + gn] : 0.0f;
        }
        __syncthreads();
#pragma unroll
        for (int kk = 0; kk < GBK; kk++) {
            float4 av = *(const float4*)&As[kk][ty * 4];
            float4 bv = *(const float4*)&Bs[kk][tx * 4];
            float a_[4] = {av.x, av.y, av.z, av.w};
            float b_[4] = {bv.x, bv.y, bv.z, bv.w};
#pragma unroll
            for (int i = 0; i < 4; i++)
#pragma unroll
                for (int j = 0; j < 4; j++)
                    acc[i][j] = fmaf(a_[i], b_[j], acc[i][j]);
        }
        __syncthreads();
    }

#pragma unroll
    for (int i = 0; i < 4; i++) {
        int gm = m0 + ty * 4 + i;
        if (gm >= M) continue;
#pragma unroll
        for (int j = 0; j < 4; j++) {
            int gn = n0 + tx * 4 + j;
            if (gn >= N) continue;
            float v = acc[i][j] + bias[gn];
            if (ACT == 2) v = (v > 0.0f) ? v : 0.01f * v;
            if (OB) Cb[(size_t)gm * N + gn] = f2bf(v);
            else    Cf[(size_t)gm * N + gn] = v;
        }
    }
}

// ======================= packs / BN / misc =================================
// A pack with split: fp32 [M,K] -> hi/lo bf16 [M,Kp], 4 elems/thread
__global__ __launch_bounds__(256) void pack_a_split(
    const float* __restrict__ in, short* __restrict__ hi, short* __restrict__ lo,
    int K, int Kp)
{
    int k4 = (blockIdx.x * 256 + threadIdx.x) * 4;
    if (k4 >= Kp) return;
    int m = blockIdx.y;
    float v[4] = {0.f, 0.f, 0.f, 0.f};
    if (k4 + 3 < K) {
        float4 f = *(const float4*)(in + (size_t)m * K + k4);
        v[0] = f.x; v[1] = f.y; v[2] = f.z; v[3] = f.w;
    } else {
#pragma unroll
        for (int j = 0; j < 4; j++)
            if (k4 + j < K) v[j] = in[(size_t)m * K + k4 + j];
    }
    unsigned hp[2], lp[2];
#pragma unroll
    for (int j = 0; j < 2; j++) {
        short h0 = f2bf(v[2 * j]), h1 = f2bf(v[2 * j + 1]);
        short l0 = f2bf(v[2 * j] - bf2f(h0)), l1 = f2bf(v[2 * j + 1] - bf2f(h1));
        hp[j] = (unsigned)(unsigned short)h0 | ((unsigned)(unsigned short)h1 << 16);
        lp[j] = (unsigned)(unsigned short)l0 | ((unsigned)(unsigned short)l1 << 16);
    }
    size_t o = (size_t)m * Kp + k4;
    *(uint2*)(hi + o) = *(uint2*)hp;
    *(uint2*)(lo + o) = *(uint2*)lp;
}

// B^T pack: in fp32 [K,N] -> bf16 [Np,Kp] transposed (zero pad)
template <int SPLITB>
__global__ __launch_bounds__(1024) void pack_bt(
    const float* __restrict__ B, short* __restrict__ bth, short* __restrict__ btl,
    int K, int N, int Kp, int Np)
{
    __shared__ float t[32][33];
    int k0 = blockIdx.x * 32, n0 = blockIdx.y * 32;
    int tx = threadIdx.x, ty = threadIdx.y;
    int gk = k0 + ty, gn = n0 + tx;
    t[ty][tx] = (gk < K && gn < N) ? B[(size_t)gk * N + gn] : 0.f;
    __syncthreads();
    int on = n0 + ty, ok = k0 + tx;
    if (on < Np && ok < Kp) {
        float v = t[tx][ty];
        short h = f2bf(v);
        size_t o = (size_t)on * Kp + ok;
        bth[o] = h;
        if (SPLITB) btl[o] = f2bf(v - bf2f(h));
    }
}

__global__ __launch_bounds__(256) void bn_stats_kernel(
    const float* __restrict__ h, float* __restrict__ csum, float* __restrict__ csq)
{
    int c = threadIdx.x;
    int r0 = blockIdx.x * 32;
    float s0 = 0, q0 = 0, s1 = 0, q1 = 0;
    for (int r = 0; r < 32; r++) {
        const float* row = h + (size_t)(r0 + r) * 512;
        float a = row[c], b = row[c + 256];
        s0 += a; q0 = fmaf(a, a, q0);
        s1 += b; q1 = fmaf(b, b, q1);
    }
    atomicAdd(&csum[c], s0);       atomicAdd(&csq[c], q0);
    atomicAdd(&csum[c + 256], s1); atomicAdd(&csq[c + 256], q1);
}

__global__ __launch_bounds__(256) void bn_apply_split(
    const float* __restrict__ h, const float* __restrict__ csum, const float* __restrict__ csq,
    const float* __restrict__ g, const float* __restrict__ b,
    short* __restrict__ hh, short* __restrict__ hl)
{
    int idx = blockIdx.x * 256 + threadIdx.x;
    int c = idx & 511;
    float mean = csum[c] * (1.0f / 4096.0f);
    float var  = csq[c] * (1.0f / 4096.0f) - mean * mean;
    float inv  = rsqrtf(var + 1e-5f);
    float v = (h[idx] - mean) * inv * g[c] + b[c];
    v = fmaxf(v, 0.0f);
    short hi = f2bf(v);
    hh[idx] = hi;
    hl[idx] = f2bf(v - bf2f(hi));
}

template <int OB>
__global__ __launch_bounds__(256) void bias_act(
    const float* __restrict__ in, const float* __restrict__ bias,
    float* __restrict__ outf, short* __restrict__ outb, int mask, int total)
{
    int i = blockIdx.x * 256 + threadIdx.x;
    if (i < total) {
        float v = in[i] + bias[i & mask];
        v = v > 0.f ? v : 0.01f * v;
        if (OB) outb[i] = f2bf(v); else outf[i] = v;
    }
}

__global__ void zero_kernel(float* p, int n) {
    int i = blockIdx.x * 256 + threadIdx.x;
    if (i < n) p[i] = 0.0f;
}

// ---- sparse incremental continuous top-k (K=50, T=0.1) --------------------
// t[i] = exp((w[i]-C)/T) maintained incrementally; only elements with
// t > s*1e-9 participate (oh < 1e-9 is a no-op in fp32 in the reference too,
// and contributes < 5e-8 to subset). s recomputed fully each iter (no
// cancellation); rebase when s < 1e-12 keeps t in range. xm out as bf16.
__global__ __launch_bounds__(256) void topk_xm_kernel(
    const float* __restrict__ wsrc, const float* __restrict__ x,
    short* __restrict__ xm, int N)
{
    __shared__ float redmx[4];
    __shared__ float red[2][4];
    const int row = blockIdx.x;
    const int tid = threadIdx.x;
    const int lane = tid & 63;
    const int wid = tid >> 6;
    const float* wr = wsrc + (size_t)row * N;
    const float* xr = x + (size_t)row * N;
    short* xmr = xm + (size_t)row * 5024;

    float t[20], sub[20];

    // load w, find block max C
    float w[20];
    float lm = -3.0e38f;
#pragma unroll
    for (int i = 0; i < 20; i++) {
        int idx = tid + (i << 8);
        w[i] = (idx < N) ? wr[idx] : -3.0e38f;
        lm = fmaxf(lm, w[i]);
        sub[i] = 0.0f;
    }
    lm = wave_max64(lm);
    if (lane == 0) redmx[wid] = lm;
    __syncthreads();
    const float C = fmaxf(fmaxf(redmx[0], redmx[1]), fmaxf(redmx[2], redmx[3]));

    // t init + initial sum
    float ls = 0.0f;
#pragma unroll
    for (int i = 0; i < 20; i++) {
        int idx = tid + (i << 8);
        t[i] = (idx < N) ? __expf((w[i] - C) * 10.0f) : 0.0f;
        ls += t[i];
    }
    ls = wave_sum64(ls);
    if (lane == 0) red[0][wid] = ls;
    __syncthreads();
    float s = red[0][0] + red[0][1] + red[0][2] + red[0][3];

    for (int it = 0; it < 50; it++) {
        const float rs = 1.0f / s;
        const float th = s * 1e-9f;
        float nls = 0.0f;
#pragma unroll
        for (int i = 0; i < 20; i++) {
            float ti = t[i];
            if (ti > th) {                       // active (rare): ~10/row/iter
                float oh = ti * rs;
                sub[i] += oh;
                float mask = fmaxf(1.0f - oh, 1e-30f);
                ti *= __expf(10.0f * __logf(mask));
                t[i] = ti;
            }
            nls += ti;
        }
        nls = wave_sum64(nls);
        int buf = (it + 1) & 1;
        if (lane == 0) red[buf][wid] = nls;
        __syncthreads();
        s = red[buf][0] + red[buf][1] + red[buf][2] + red[buf][3];
        if (s < 1e-12f) {                        // uniform branch: rebase
            float inv = 1.0f / s;
#pragma unroll
            for (int i = 0; i < 20; i++) t[i] *= inv;
            s = 1.0f;
        }
    }

#pragma unroll
    for (int i = 0; i < 20; i++) {
        int idx = tid + (i << 8);
        if (idx < 5024) xmr[idx] = (idx < N) ? f2bf(xr[idx] * sub[i]) : (short)0;
    }
}

__global__ void reparam_kernel(const float* __restrict__ mu, const float* __restrict__ lv,
                               const float* __restrict__ eps, float* __restrict__ z, int n)
{
    int i = blockIdx.x * 256 + threadIdx.x;
    if (i < n) z[i] = fmaf(eps[i], expf(0.5f * lv[i]), mu[i]);
}

// ---------------------------------------------------------------------------
extern "C" void kernel_launch(void* const* d_in, const int* in_sizes, int n_in,
                              void* d_out, int out_size, void* d_ws, size_t ws_size,
                              hipStream_t stream)
{
    const float* x      = (const float*)d_in[0];
    const float* noise  = (const float*)d_in[1];
    const float* epsv   = (const float*)d_in[2];
    const float* wc_w1  = (const float*)d_in[3];
    const float* bn_g   = (const float*)d_in[5];
    const float* bn_b   = (const float*)d_in[6];
    const float* wc_w2  = (const float*)d_in[7];
    const float* wc_b2  = (const float*)d_in[8];
    const float* enc_w1 = (const float*)d_in[9];
    const float* enc_b1 = (const float*)d_in[10];
    const float* enc_w2 = (const float*)d_in[11];
    const float* enc_b2 = (const float*)d_in[12];
    const float* enc_w3 = (const float*)d_in[13];
    const float* enc_b3 = (const float*)d_in[14];
    const float* enc_w4 = (const float*)d_in[15];
    const float* enc_b4 = (const float*)d_in[16];
    const float* mean_w = (const float*)d_in[17];
    const float* mean_b = (const float*)d_in[18];
    const float* lv_w   = (const float*)d_in[19];
    const float* lv_b   = (const float*)d_in[20];
    const float* dec_w1 = (const float*)d_in[21];
    const float* dec_b1 = (const float*)d_in[22];
    const float* dec_w2 = (const float*)d_in[23];
    const float* dec_b2 = (const float*)d_in[24];

    const int B = 4096, D = 5000, H = 512, Z = 64;
    const int Dk = 5024;   // D padded to 32 (K pad)
    const int Dn = 5120;   // D padded to 128 (N pad for Bt rows)

    float* out  = (float*)d_out;
    float* mu_x = out;                        // also holds w until topk
    float* mu_l = out + (size_t)B * D;
    float* lv_l = mu_l + (size_t)B * Z;
    float* w_buf = mu_x;

    char* base = (char*)d_ws;
    size_t off = 0;
    auto alloc = [&](size_t bytes) { size_t r = off; off += (bytes + 255) & ~(size_t)255; return r; };
    const size_t XS = (size_t)B * Dk;
    size_t o_xhi   = alloc(XS * 2);               // x_hi  -> later xm_bf16
    size_t o_xlo   = alloc(XS * 2);               // x_lo  -> later e1_acc | e1_bf16 | e2_acc
    size_t o_bufh  = alloc((size_t)B * H * 4);
    size_t o_hhi   = alloc((size_t)B * H * 2);
    size_t o_hlo   = alloc((size_t)B * H * 2);
    size_t o_e2b   = alloc((size_t)B * H * 2);
    size_t o_e3a   = alloc((size_t)B * H * 4);
    size_t o_e3b   = alloc((size_t)B * H * 2);
    size_t o_e4    = alloc((size_t)B * H * 4);
    size_t o_z     = alloc((size_t)B * Z * 4);
    size_t o_dbf   = alloc((size_t)B * 2 * H * 2);
    size_t o_csum  = alloc(512 * 4);
    size_t o_csq   = alloc(512 * 4);
    size_t o_w1th  = alloc((size_t)H * Dk * 2);
    size_t o_w1tl  = alloc((size_t)H * Dk * 2);
    size_t o_w2th  = alloc((size_t)Dn * H * 2);
    size_t o_w2tl  = alloc((size_t)Dn * H * 2);
    size_t o_e1wt  = alloc((size_t)(2 * H) * Dk * 2);
    size_t o_e2wt  = alloc((size_t)H * (2 * H) * 2);
    size_t o_e3wt  = alloc((size_t)H * H * 2);
    size_t o_e4wt  = alloc((size_t)H * H * 2);
    size_t o_d2wt  = alloc((size_t)Dn * (2 * H) * 2);

    short* x_hi  = (short*)(base + o_xhi);
    short* x_lo  = (short*)(base + o_xlo);
    short* xm_bf = (short*)(base + o_xhi);
    float* e1_acc = (float*)(base + o_xlo);
    short* e1_bf  = (short*)(base + o_xlo + (size_t)B * 2 * H * 4);
    float* e2_acc = (float*)(base + o_xlo + (size_t)B * 2 * H * 4 + (size_t)B * 2 * H * 2);
    float* buf_h = (float*)(base + o_bufh);
    short* h_hi  = (short*)(base + o_hhi);
    short* h_lo  = (short*)(base + o_hlo);
    short* e2_bf = (short*)(base + o_e2b);
    float* e3_acc = (float*)(base + o_e3a);
    short* e3_bf = (short*)(base + o_e3b);
    float* e4    = (float*)(base + o_e4);
    float* zbuf  = (float*)(base + o_z);
    short* d_bf  = (short*)(base + o_dbf);
    float* csum  = (float*)(base + o_csum);
    float* csq   = (float*)(base + o_csq);
    short* w1t_h = (short*)(base + o_w1th);
    short* w1t_l = (short*)(base + o_w1tl);
    short* w2t_h = (short*)(base + o_w2th);
    short* w2t_l = (short*)(base + o_w2tl);
    short* e1wt  = (short*)(base + o_e1wt);
    short* e2wt  = (short*)(base + o_e2wt);
    short* e3wt  = (short*)(base + o_e3wt);
    short* e4wt  = (short*)(base + o_e4wt);
    short* d2wt  = (short*)(base + o_d2wt);

    dim3 tb(32, 32);

    // ---- packs ----
    pack_a_split<<<dim3((Dk / 4 + 255) / 256, B), 256, 0, stream>>>(x, x_hi, x_lo, D, Dk);
    pack_bt<1><<<dim3(Dk / 32, H / 32), tb, 0, stream>>>(wc_w1, w1t_h, w1t_l, D, H, Dk, H);
    pack_bt<1><<<dim3(H / 32, Dn / 32), tb, 0, stream>>>(wc_w2, w2t_h, w2t_l, H, D, H, Dn);
    pack_bt<0><<<dim3(Dk / 32, 2 * H / 32), tb, 0, stream>>>(enc_w1, e1wt, nullptr, D, 2 * H, Dk, 2 * H);
    pack_bt<0><<<dim3(2 * H / 32, H / 32), tb, 0, stream>>>(enc_w2, e2wt, nullptr, 2 * H, H, 2 * H, H);
    pack_bt<0><<<dim3(H / 32, H / 32), tb, 0, stream>>>(enc_w3, e3wt, nullptr, H, H, H, H);
    pack_bt<0><<<dim3(H / 32, H / 32), tb, 0, stream>>>(enc_w4, e4wt, nullptr, H, H, H, H);
    pack_bt<0><<<dim3(2 * H / 32, Dn / 32), tb, 0, stream>>>(dec_w2, d2wt, nullptr, 2 * H, D, 2 * H, Dn);

    // ---- weight_creator: h = x@wc_w1 (SPLIT, SK=4, atomic) ----
    zero_kernel<<<(B * H + 255) / 256, 256, 0, stream>>>(buf_h, B * H);
    zero_kernel<<<4, 256, 0, stream>>>(csum, 1024);
    gemm_mfma<1, 0, 0, 1, 0><<<dim3(H / 128, B / 128, 4), 256, 0, stream>>>(
        x_hi, x_lo, w1t_h, w1t_l, nullptr, nullptr, buf_h, nullptr, H, Dk);
    bn_stats_kernel<<<128, 256, 0, stream>>>(buf_h, csum, csq);
    bn_apply_split<<<B * H / 256, 256, 0, stream>>>(buf_h, csum, csq, bn_g, bn_b, h_hi, h_lo);

    // ---- w = h@wc_w2 + b2 + gumbel (SPLIT, SK=1, fused epilogue) ----
    gemm_mfma<1, 0, 1, 0, 0><<<dim3((D + 127) / 128, B / 128, 1), 256, 0, stream>>>(
        h_hi, h_lo, w2t_h, w2t_l, wc_b2, noise, w_buf, nullptr, D, H);

    // ---- continuous top-k + mask -> xm bf16 ----
    topk_xm_kernel<<<B, 256, 0, stream>>>(w_buf, x, xm_bf, D);

    // ---- encoder ----
    zero_kernel<<<(B * 2 * H + 255) / 256, 256, 0, stream>>>(e1_acc, B * 2 * H);
    gemm_mfma<0, 0, 0, 1, 0><<<dim3(2 * H / 128, B / 128, 2), 256, 0, stream>>>(
        xm_bf, nullptr, e1wt, nullptr, nullptr, nullptr, e1_acc, nullptr, 2 * H, Dk);
    bias_act<1><<<(B * 2 * H + 255) / 256, 256, 0, stream>>>(e1_acc, enc_b1, nullptr, e1_bf, 2 * H - 1, B * 2 * H);

    zero_kernel<<<(B * H + 255) / 256, 256, 0, stream>>>(e2_acc, B * H);
    gemm_mfma<0, 0, 0, 1, 0><<<dim3(H / 128, B / 128, 4), 256, 0, stream>>>(
        e1_bf, nullptr, e2wt, nullptr, nullptr, nullptr, e2_acc, nullptr, H, 2 * H);
    bias_act<1><<<(B * H + 255) / 256, 256, 0, stream>>>(e2_acc, enc_b2, nullptr, e2_bf, H - 1, B * H);

    zero_kernel<<<(B * H + 255) / 256, 256, 0, stream>>>(e3_acc, B * H);
    gemm_mfma<0, 0, 0, 1, 0><<<dim3(H / 128, B / 128, 4), 256, 0, stream>>>(
        e2_bf, nullptr, e3wt, nullptr, nullptr, nullptr, e3_acc, nullptr, H, H);
    bias_act<1><<<(B * H + 255) / 256, 256, 0, stream>>>(e3_acc, enc_b3, nullptr, e3_bf, H - 1, B * H);

    zero_kernel<<<(B * H + 255) / 256, 256, 0, stream>>>(e4, B * H);
    gemm_mfma<0, 0, 0, 1, 0><<<dim3(H / 128, B / 128, 4), 256, 0, stream>>>(
        e3_bf, nullptr, e4wt, nullptr, nullptr, nullptr, e4, nullptr, H, H);
    bias_act<0><<<(B * H + 255) / 256, 256, 0, stream>>>(e4, enc_b4, e4, nullptr, H - 1, B * H);

    // ---- latent heads + reparameterize ----
    gemm_f32<0, 0><<<dim3(1, B / 64), 256, 0, stream>>>(e4, mean_w, mean_b, mu_l, nullptr, B, Z, H);
    gemm_f32<0, 0><<<dim3(1, B / 64), 256, 0, stream>>>(e4, lv_w, lv_b, lv_l, nullptr, B, Z, H);
    reparam_kernel<<<(B * Z + 255) / 256, 256, 0, stream>>>(mu_l, lv_l, epsv, zbuf, B * Z);

    // ---- decoder ----
    gemm_f32<2, 1><<<dim3(2 * H / 64, B / 64), 256, 0, stream>>>(zbuf, dec_w1, dec_b1, nullptr, d_bf, B, 2 * H, Z);
    gemm_mfma<0, 3, 0, 0, 0><<<dim3((D + 127) / 128, B / 128, 1), 256, 0, stream>>>(
        d_bf, nullptr, d2wt, nullptr, dec_b2, nullptr, mu_x, nullptr, D, 2 * H);
}